// Round 4
// baseline (2995.851 us; speedup 1.0000x reference)
//
#include <hip/hip_runtime.h>
#include <math.h>

typedef unsigned short ushort_t;
typedef unsigned int uint_t;

constexpr int Bb = 32, Ll = 64, Nn = 8;
constexpr int IMGS = Bb * Ll * Nn;          // 16384
constexpr int Cc = 3, Hh = 40, Ww = 40;     // input image
constexpr int OC1 = 32, O1 = 9;             // conv1: 8x8 s4 -> 9x9
constexpr int OC2 = 64;                     // conv2: 4x4 s2 -> 3x3
constexpr int HID = 64, G3 = 192, NACT = 8;

__device__ inline float bf2f(ushort_t u) {
  union { uint_t i; float f; } v; v.i = ((uint_t)u) << 16; return v.f;
}
__device__ inline void unpack2(uint_t u, float& lo, float& hi) {
  union { uint_t i; float f; } a, b;
  a.i = u << 16; b.i = u & 0xffff0000u;
  lo = a.f; hi = b.f;
}
// read element idx of a buffer whose storage is f32 (isbf=0) or bf16 (isbf=1)
__device__ inline float ld1(const void* p, int idx, int isbf) {
  return isbf ? bf2f(((const ushort_t*)p)[idx]) : ((const float*)p)[idx];
}

// ---------------- dtype detect: bf16 data has sane exponents; f32 misread as bf16 doesn't ----
__global__ __launch_bounds__(256) void detect_kernel(
    const ushort_t* __restrict__ obs, const ushort_t* __restrict__ whh,
    int* __restrict__ flags) {
  __shared__ int cnt[2];
  if (threadIdx.x < 2) cnt[threadIdx.x] = 0;
  __syncthreads();
  int bad0 = 0, bad1 = 0;
  for (int i = threadIdx.x; i < 4096; i += 256) {
    int e0 = (obs[i] >> 7) & 0xFF; if (e0 >= 0xC0) bad0++;   // |x| >= 2^65: impossible for real data
    int e1 = (whh[i] >> 7) & 0xFF; if (e1 >= 0xC0) bad1++;
  }
  atomicAdd(&cnt[0], bad0);
  atomicAdd(&cnt[1], bad1);
  __syncthreads();
  if (threadIdx.x == 0) { flags[0] = (cnt[0] <= 4); flags[1] = (cnt[1] <= 4); }
}

// ---------------- weight repack (+ optional bf16->f32) ----------------
// w1:  (32,3,8,8)  -> w1p[t] identity f32                 [6144]
// w2:  (64,32,4,4) -> w2p[(ic*16+ky*4+kx)*64 + oc]        [512][64]
// w3:  (64,64,3,3) -> w3p[(ic*9+ky*3+kx)*64 + oc]         [576][64]
// wih: (192,64)    -> wihp[k*192 + g]                     [64][192]
__global__ __launch_bounds__(256) void repack_kernel(
    const void* __restrict__ w1, const void* __restrict__ w2,
    const void* __restrict__ w3, const void* __restrict__ wih,
    const int* __restrict__ flags,
    float* __restrict__ w1p, float* __restrict__ w2p,
    float* __restrict__ w3p, float* __restrict__ wihp) {
  const int fw = flags[1];
  int t = blockIdx.x * 256 + threadIdx.x;
  if (t < 32 * 192) { w1p[t] = ld1(w1, t, fw); }
  if (t < 64 * 512) { int oc = t >> 9; int r = t & 511; w2p[r * 64 + oc] = ld1(w2, t, fw); }
  if (t < 64 * 576) { int oc = t / 576; int r = t - oc * 576; w3p[r * 64 + oc] = ld1(w3, t, fw); }
  if (t < 192 * 64) { int g = t >> 6; int k = t & 63; wihp[k * 192 + g] = ld1(wih, t, fw); }
}

// ---------------- fused conv1+conv2+conv3+gi, one block per image ----------------
__global__ __launch_bounds__(256) void conv_fused_kernel(
    const void* __restrict__ obs,
    const float* __restrict__ w1p, const void* __restrict__ b1,
    const void* __restrict__ b2, const void* __restrict__ b3,
    const float* __restrict__ w2p, const float* __restrict__ w3p,
    const float* __restrict__ wihp, const int* __restrict__ flags,
    float* __restrict__ gi) {
  __shared__ float s_in[Cc * Hh * Ww];      // 4800 f32
  __shared__ float s_f1[OC1][O1][12];       // conv1 out, padded rows
  __shared__ float s_f2[OC2][12];           // conv2 out, 9 used
  __shared__ float s_f3[HID];               // conv3 out
  __shared__ float s_red[OC2 * 4 * 9];      // reduction scratch

  const int tid = threadIdx.x;
  const int img = blockIdx.x;
  const int fobs = flags[0], fw = flags[1];

  // stage input image -> f32 LDS (dual dtype path, both coalesced 16B)
  if (fobs) {
    const uint4* src = reinterpret_cast<const uint4*>((const ushort_t*)obs + (size_t)img * (Cc * Hh * Ww));
    for (int i = tid; i < (Cc * Hh * Ww) / 8; i += 256) {
      uint4 v = src[i];
      float* d = &s_in[i * 8];
      unpack2(v.x, d[0], d[1]);
      unpack2(v.y, d[2], d[3]);
      unpack2(v.z, d[4], d[5]);
      unpack2(v.w, d[6], d[7]);
    }
  } else {
    const float4* src = reinterpret_cast<const float4*>((const float*)obs + (size_t)img * (Cc * Hh * Ww));
    for (int i = tid; i < (Cc * Hh * Ww) / 4; i += 256) {
      float4 v = src[i];
      float* d = &s_in[i * 4];
      d[0] = v.x; d[1] = v.y; d[2] = v.z; d[3] = v.w;
    }
  }
  __syncthreads();

  // ---- conv1: wave -> 8 oc, lane -> spatial (sp and sp+64) ----
  {
    const int wave = tid >> 6, lane = tid & 63;
    const int ocb = wave * 8;
    const int sp0 = lane, sp1 = lane + 64;
    const int oy0 = sp0 / 9, ox0 = sp0 - oy0 * 9;
    const bool has1 = (sp1 < 81);
    const int oy1 = has1 ? sp1 / 9 : 0;
    const int ox1 = has1 ? (sp1 - (sp1 / 9) * 9) : 0;

    float acc0[8], acc1[8];
#pragma unroll
    for (int o = 0; o < 8; ++o) { acc0[o] = ld1(b1, ocb + o, fw); acc1[o] = acc0[o]; }

    for (int ic = 0; ic < 3; ++ic) {
#pragma unroll
      for (int ky = 0; ky < 8; ++ky) {
        const float* r0p = &s_in[(ic * 40 + oy0 * 4 + ky) * 40 + ox0 * 4];
        float4 a0 = *reinterpret_cast<const float4*>(r0p);
        float4 a1 = *reinterpret_cast<const float4*>(r0p + 4);
        float4 c0 = a0, c1 = a1;
        if (has1) {
          const float* r1p = &s_in[(ic * 40 + oy1 * 4 + ky) * 40 + ox1 * 4];
          c0 = *reinterpret_cast<const float4*>(r1p);
          c1 = *reinterpret_cast<const float4*>(r1p + 4);
        }
        const float* wp = w1p + ocb * 192 + ic * 64 + ky * 8;
#pragma unroll
        for (int o = 0; o < 8; ++o) {
          float4 w0 = *reinterpret_cast<const float4*>(wp + o * 192);
          float4 w4 = *reinterpret_cast<const float4*>(wp + o * 192 + 4);
          acc0[o] += w0.x * a0.x + w0.y * a0.y + w0.z * a0.z + w0.w * a0.w
                   + w4.x * a1.x + w4.y * a1.y + w4.z * a1.z + w4.w * a1.w;
          acc1[o] += w0.x * c0.x + w0.y * c0.y + w0.z * c0.z + w0.w * c0.w
                   + w4.x * c1.x + w4.y * c1.y + w4.z * c1.z + w4.w * c1.w;
        }
      }
    }
#pragma unroll
    for (int o = 0; o < 8; ++o) {
      s_f1[ocb + o][oy0][ox0] = fmaxf(acc0[o], 0.f);
      if (has1) s_f1[ocb + o][oy1][ox1] = fmaxf(acc1[o], 0.f);
    }
  }
  __syncthreads();

  // ---- conv2: thread -> (oc, k-quarter over ic) ----
  {
    const int oc = tid & 63, q = tid >> 6;
    float a2[9];
#pragma unroll
    for (int s = 0; s < 9; ++s) a2[s] = 0.f;
    for (int i = 0; i < 8; ++i) {
      const int ic = q * 8 + i;
#pragma unroll
      for (int ky = 0; ky < 4; ++ky) {
        float r[3][8];
#pragma unroll
        for (int oy = 0; oy < 3; ++oy) {
          const float* rp = &s_f1[ic][oy * 2 + ky][0];
          float4 v0 = *reinterpret_cast<const float4*>(rp);
          float4 v1 = *reinterpret_cast<const float4*>(rp + 4);
          r[oy][0] = v0.x; r[oy][1] = v0.y; r[oy][2] = v0.z; r[oy][3] = v0.w;
          r[oy][4] = v1.x; r[oy][5] = v1.y; r[oy][6] = v1.z; r[oy][7] = v1.w;
        }
        const float* wp = w2p + (ic * 16 + ky * 4) * 64 + oc;
#pragma unroll
        for (int kx = 0; kx < 4; ++kx) {
          const float w = wp[kx * 64];
#pragma unroll
          for (int oy = 0; oy < 3; ++oy)
#pragma unroll
            for (int ox = 0; ox < 3; ++ox)
              a2[oy * 3 + ox] += w * r[oy][ox * 2 + kx];
        }
      }
    }
#pragma unroll
    for (int s = 0; s < 9; ++s) s_red[(oc * 4 + q) * 9 + s] = a2[s];
  }
  __syncthreads();
  // BUGFIX (R1/R3 root cause): 576 work items, 256 threads -> must LOOP, not `if (tid < 576)`
  for (int i = tid; i < 576; i += 256) {
    const int oc = i / 9, sp = i - oc * 9;
    float v = ld1(b2, oc, fw);
#pragma unroll
    for (int q = 0; q < 4; ++q) v += s_red[(oc * 4 + q) * 9 + sp];
    s_f2[oc][sp] = fmaxf(v, 0.f);
  }
  __syncthreads();

  // ---- conv3: thread -> (oc, k-quarter over ic) ----
  {
    const int oc = tid & 63, q = tid >> 6;
    float a3 = 0.f;
    for (int i = 0; i < 16; ++i) {
      const int ic = q * 16 + i;
      const float* wp = w3p + ic * 9 * 64 + oc;
#pragma unroll
      for (int j = 0; j < 9; ++j) a3 += s_f2[ic][j] * wp[j * 64];
    }
    s_red[tid] = a3;  // tid = q*64+oc
  }
  __syncthreads();
  if (tid < 64) {
    float v = ld1(b3, tid, fw) + s_red[tid] + s_red[64 + tid] + s_red[128 + tid] + s_red[192 + tid];
    s_f3[tid] = fmaxf(v, 0.f);
  }
  __syncthreads();

  // ---- gi = feats @ w_ih^T (b_ih added in GRU) ----
  if (tid < 192) {
    float v = 0.f;
    for (int k = 0; k < 64; ++k) v += s_f3[k] * wihp[k * 192 + tid];
    gi[(size_t)img * G3 + tid] = v;
  }
}

// ---------------- GRU: one block (1 wave) per (b,n) sequence ----------------
__global__ __launch_bounds__(64) void gru_kernel(
    const float* __restrict__ gi, const void* __restrict__ h0,
    const void* __restrict__ whh, const void* __restrict__ bih,
    const void* __restrict__ bhh, const int* __restrict__ flags,
    float* __restrict__ rnn, float* __restrict__ hout) {
  __shared__ float s_w[G3 * 68];   // row stride 68 (16B aligned)
  __shared__ float s_h[HID];
  const int j = threadIdx.x;
  const int s = blockIdx.x;
  const int fw = flags[1];

  if (fw) {
    const uint4* wsrc = reinterpret_cast<const uint4*>(whh);
    for (int v = j; v < (G3 * HID) / 8; v += 64) {
      uint4 w = wsrc[v];
      int i8 = v * 8;
      float* d = &s_w[(i8 >> 6) * 68 + (i8 & 63)];
      unpack2(w.x, d[0], d[1]);
      unpack2(w.y, d[2], d[3]);
      unpack2(w.z, d[4], d[5]);
      unpack2(w.w, d[6], d[7]);
    }
  } else {
    const float4* wsrc = reinterpret_cast<const float4*>(whh);
    for (int v = j; v < (G3 * HID) / 4; v += 64) {
      float4 w = wsrc[v];
      int i4 = v * 4;
      float* d = &s_w[(i4 >> 6) * 68 + (i4 & 63)];
      d[0] = w.x; d[1] = w.y; d[2] = w.z; d[3] = w.w;
    }
  }
  float h = ld1(h0, s * HID + j, fw);
  s_h[j] = h;
  const float bir = ld1(bih, j, fw), biz = ld1(bih, 64 + j, fw), bin_ = ld1(bih, 128 + j, fw);
  const float bhr = ld1(bhh, j, fw), bhz = ld1(bhh, 64 + j, fw), bhn = ld1(bhh, 128 + j, fw);
  const int b = s >> 3, n = s & 7;
  const float* gbase = gi + ((size_t)b * Ll * Nn + n) * G3;
  float* rbase = rnn + ((size_t)b * Ll * Nn + n) * HID;
  __syncthreads();

  const float* wr = &s_w[j * 68];
  const float* wz = &s_w[(64 + j) * 68];
  const float* wn = &s_w[(128 + j) * 68];

  for (int l = 0; l < Ll; ++l) {
    const float* g = gbase + (size_t)l * Nn * G3;
    float hr = bhr, hz = bhz, hn = bhn;
#pragma unroll 4
    for (int k = 0; k < 64; k += 4) {
      float4 hv = *reinterpret_cast<const float4*>(&s_h[k]);
      float4 w0 = *reinterpret_cast<const float4*>(wr + k);
      float4 w1v = *reinterpret_cast<const float4*>(wz + k);
      float4 w2v = *reinterpret_cast<const float4*>(wn + k);
      hr += w0.x * hv.x + w0.y * hv.y + w0.z * hv.z + w0.w * hv.w;
      hz += w1v.x * hv.x + w1v.y * hv.y + w1v.z * hv.z + w1v.w * hv.w;
      hn += w2v.x * hv.x + w2v.y * hv.y + w2v.z * hv.z + w2v.w * hv.w;
    }
    const float gr = g[j] + bir + hr;
    const float gz = g[64 + j] + biz + hz;
    const float gn = g[128 + j] + bin_;
    const float r = 1.f / (1.f + __expf(-gr));
    const float z = 1.f / (1.f + __expf(-gz));
    const float nn_ = tanhf(gn + r * hn);
    h = (1.f - z) * nn_ + z * h;
    __syncthreads();           // all lanes done reading old s_h
    s_h[j] = h;
    rbase[(size_t)l * Nn * HID + j] = h;
    __syncthreads();           // new h visible
  }
  hout[(size_t)s * HID + j] = h;
}

// ---------------- FC: q = rnn @ fc_w^T + fc_b ----------------
__global__ __launch_bounds__(256) void fc_kernel(
    const float* __restrict__ rnn, const void* __restrict__ fcw,
    const void* __restrict__ fcb, const int* __restrict__ flags,
    float* __restrict__ q) {
  __shared__ float s_w[NACT * HID];
  __shared__ float s_b[NACT];
  const int tid = threadIdx.x;
  const int fw = flags[1];
  for (int i = tid; i < NACT * HID; i += 256) s_w[i] = ld1(fcw, i, fw);
  if (tid < NACT) s_b[tid] = ld1(fcb, tid, fw);
  __syncthreads();
  const int row = blockIdx.x * 256 + tid;
  float x[64];
  const float4* xp = reinterpret_cast<const float4*>(rnn + (size_t)row * HID);
#pragma unroll
  for (int i = 0; i < 16; ++i) {
    float4 v = xp[i];
    x[4 * i] = v.x; x[4 * i + 1] = v.y; x[4 * i + 2] = v.z; x[4 * i + 3] = v.w;
  }
#pragma unroll
  for (int a = 0; a < NACT; ++a) {
    float v = s_b[a];
#pragma unroll
    for (int k = 0; k < 64; ++k) v += x[k] * s_w[a * 64 + k];
    q[(size_t)row * NACT + a] = v;
  }
}

extern "C" void kernel_launch(void* const* d_in, const int* in_sizes, int n_in,
                              void* d_out, int out_size, void* d_ws, size_t ws_size,
                              hipStream_t stream) {
  const void* obs = d_in[0];
  const void* h0  = d_in[1];
  const void* w1  = d_in[2];
  const void* b1  = d_in[3];
  const void* w2  = d_in[4];
  const void* b2  = d_in[5];
  const void* w3  = d_in[6];
  const void* b3  = d_in[7];
  const void* wih = d_in[8];
  const void* whh = d_in[9];
  const void* bih = d_in[10];
  const void* bhh = d_in[11];
  const void* fcw = d_in[12];
  const void* fcb = d_in[13];

  float* qout = (float*)d_out;                        // (B,L,N,8) f32
  float* hout = qout + (size_t)IMGS * NACT;           // (B,N,64)  f32

  // workspace layout (~17.1 MB)
  char* wsb = (char*)d_ws;
  int*   flags = (int*)wsb;                           // [4] @0
  float* w1p   = (float*)(wsb + 16);                  // 6144 f32
  float* w2p   = w1p + 6144;                          // 32768 f32
  float* w3p   = w2p + 32768;                         // 36864 f32
  float* wihp  = w3p + 36864;                         // 12288 f32
  float* gi    = wihp + 12288;                        // [IMGS][192] f32
  float* rnn   = gi + (size_t)IMGS * G3;              // [IMGS][64] f32

  detect_kernel<<<1, 256, 0, stream>>>((const ushort_t*)obs, (const ushort_t*)whh, flags);
  repack_kernel<<<144, 256, 0, stream>>>(w1, w2, w3, wih, flags, w1p, w2p, w3p, wihp);
  conv_fused_kernel<<<IMGS, 256, 0, stream>>>(obs, w1p, b1, b2, b3, w2p, w3p, wihp, flags, gi);
  gru_kernel<<<256, 64, 0, stream>>>(gi, h0, whh, bih, bhh, flags, rnn, hout);
  fc_kernel<<<IMGS / 256, 256, 0, stream>>>(rnn, fcw, fcb, flags, qout);
}

// Round 5
// 424.840 us; speedup vs baseline: 7.0517x; 7.0517x over previous
//
#include <hip/hip_runtime.h>
#include <math.h>

typedef unsigned short ushort_t;
typedef unsigned int uint_t;
typedef __attribute__((ext_vector_type(8))) short short8_t;   // 8 bf16 (4 VGPR)
typedef __attribute__((ext_vector_type(4))) float f32x4_t;    // MFMA accumulator

constexpr int Bb = 32, Ll = 64, Nn = 8;
constexpr int IMGS = Bb * Ll * Nn;          // 16384
constexpr int Cc = 3, Hh = 40, Ww = 40;
constexpr int HID = 64, G3 = 192, NACT = 8;

__device__ inline float bf2f(ushort_t u) {
  union { uint_t i; float f; } v; v.i = ((uint_t)u) << 16; return v.f;
}
__device__ inline ushort_t f2bf(float f) {   // RNE
  union { float f; uint_t u; } v; v.f = f;
  uint_t r = v.u + 0x7fffu + ((v.u >> 16) & 1u);
  return (ushort_t)(r >> 16);
}
__device__ inline void unpack2(uint_t u, float& lo, float& hi) {
  union { uint_t i; float f; } a, b;
  a.i = u << 16; b.i = u & 0xffff0000u;
  lo = a.f; hi = b.f;
}
__device__ inline float ld1(const void* p, int idx, int isbf) {
  return isbf ? bf2f(((const ushort_t*)p)[idx]) : ((const float*)p)[idx];
}
__device__ inline short8_t ldsh8(const ushort_t* p) {   // 16B from LDS as 2x b64
  union { short8_t v; uint2 u[2]; } r;
  r.u[0] = *(const uint2*)p;
  r.u[1] = *(const uint2*)(p + 4);
  return r.v;
}
__device__ inline short8_t ldg8(const ushort_t* p) {    // 16B global
  union { short8_t v; uint4 u; } r;
  r.u = *(const uint4*)p;
  return r.v;
}

// ---------------- dtype detect (insurance; verified f32 world in R4) ----------------
__global__ __launch_bounds__(256) void detect_kernel(
    const ushort_t* __restrict__ obs, const ushort_t* __restrict__ whh,
    int* __restrict__ flags) {
  __shared__ int cnt[2];
  if (threadIdx.x < 2) cnt[threadIdx.x] = 0;
  __syncthreads();
  int bad0 = 0, bad1 = 0;
  for (int i = threadIdx.x; i < 4096; i += 256) {
    int e0 = (obs[i] >> 7) & 0xFF; if (e0 >= 0xC0) bad0++;
    int e1 = (whh[i] >> 7) & 0xFF; if (e1 >= 0xC0) bad1++;
  }
  atomicAdd(&cnt[0], bad0);
  atomicAdd(&cnt[1], bad1);
  __syncthreads();
  if (threadIdx.x == 0) { flags[0] = (cnt[0] <= 4); flags[1] = (cnt[1] <= 4); }
}

// ---------------- weight repack -> bf16 packed for MFMA ----------------
// w1pack[oc][k],  k = ic*64+ky*8+kx          (native order)       [32][192]
// w2pack[oc][k],  k = (ky*4+kx)*32 + ic      (ic fastest!)        [64][512]
// w3pb [(ic*9+j)*64 + oc]  bf16                                    [576][64]
// wihp [k*192 + g] f32                                             [64][192]
__global__ __launch_bounds__(256) void repack_kernel(
    const void* __restrict__ w1, const void* __restrict__ w2,
    const void* __restrict__ w3, const void* __restrict__ wih,
    const int* __restrict__ flags,
    ushort_t* __restrict__ w1pack, ushort_t* __restrict__ w2pack,
    ushort_t* __restrict__ w3pb, float* __restrict__ wihp) {
  const int fw = flags[1];
  int t = blockIdx.x * 256 + threadIdx.x;
  if (t < 6144) w1pack[t] = f2bf(ld1(w1, t, fw));
  if (t < 32768) {
    int oc = t >> 9, r = t & 511;
    int kykx = r >> 5, ic = r & 31;
    w2pack[t] = f2bf(ld1(w2, oc * 512 + ic * 16 + kykx, fw));
  }
  if (t < 36864) {
    int oc = t & 63, rem = t >> 6;           // rem = ic*9 + j
    w3pb[t] = f2bf(ld1(w3, oc * 576 + rem, fw));
  }
  if (t < 12288) {
    int g = t >> 6, k = t & 63;
    wihp[k * 192 + g] = ld1(wih, t, fw);
  }
}

// ---------------- fused conv tower (MFMA) + gi, one block per image ----------------
__global__ __launch_bounds__(256) void conv_mfma_kernel(
    const void* __restrict__ obs,
    const ushort_t* __restrict__ w1pack, const ushort_t* __restrict__ w2pack,
    const ushort_t* __restrict__ w3pb,
    const void* __restrict__ b1, const void* __restrict__ b2, const void* __restrict__ b3,
    const float* __restrict__ wihp, const int* __restrict__ flags,
    float* __restrict__ gi) {
  __shared__ __attribute__((aligned(16))) ushort_t s_in[Cc * Hh * Ww];  // bf16 image, 9.6 KB
  __shared__ __attribute__((aligned(16))) ushort_t s_f1[81 * 40];       // f1[pix][oc], pix stride 40, 6.5 KB
  __shared__ float s_f2[9][68];                                         // f2[pix][oc]
  __shared__ float s_f3[HID];
  __shared__ float s_red[256];

  const int tid = threadIdx.x;
  const int img = blockIdx.x;
  const int fobs = flags[0], fw = flags[1];

  // ---- stage obs -> bf16 LDS ----
  if (fobs) {  // input already bf16: straight 16B copies
    const uint4* src = reinterpret_cast<const uint4*>((const ushort_t*)obs + (size_t)img * 4800);
    uint4* dst = reinterpret_cast<uint4*>(s_in);
    for (int i = tid; i < 600; i += 256) dst[i] = src[i];
  } else {     // f32 input: load float4, convert RNE, store 8B
    const float4* src = reinterpret_cast<const float4*>((const float*)obs + (size_t)img * 4800);
    uint2* dst = reinterpret_cast<uint2*>(s_in);
    for (int i = tid; i < 1200; i += 256) {
      float4 v = src[i];
      uint2 o;
      o.x = (uint_t)f2bf(v.x) | ((uint_t)f2bf(v.y) << 16);
      o.y = (uint_t)f2bf(v.z) | ((uint_t)f2bf(v.w) << 16);
      dst[i] = o;
    }
  }
  __syncthreads();

  const int wave = tid >> 6, lane = tid & 63;
  const int lrow = lane & 15;    // A-row / B-col / D-col selector
  const int lk8  = lane >> 4;    // k-octet selector (0..3)

  // ---- conv1: implicit GEMM  M=81(pad 96) x N=32 x K=192 ----
  // A[m][k] = s_in[ic*1600 + (oy*4+ky)*40 + ox*4 + kx], k=ic*64+ky*8+kx (8-contig)
  // wave -> ntile = wave&1, mtiles = (wave>>1)*3 + {0,1,2}
  {
    const int nt = wave & 1, mt0 = (wave >> 1) * 3;
    int ab0, ab1, ab2;
    {
      int p0 = mt0 * 16 + lrow;      if (p0 > 80) p0 = 80;
      int p1 = p0 + 16;              if (p1 > 80) p1 = 80;
      int p2 = p0 + 32;              if (p2 > 80) p2 = 80;
      ab0 = (p0 / 9) * 160 + (p0 % 9) * 4;
      ab1 = (p1 / 9) * 160 + (p1 % 9) * 4;
      ab2 = (p2 / 9) * 160 + (p2 % 9) * 4;
    }
    const ushort_t* wrow = w1pack + (nt * 16 + lrow) * 192 + lk8 * 8;
    f32x4_t acc0 = {0.f, 0.f, 0.f, 0.f}, acc1 = acc0, acc2 = acc0;
#pragma unroll
    for (int ks = 0; ks < 6; ++ks) {
      const int g = ks * 4 + lk8;                       // 8-elem k-group 0..23
      const int aoff = (g >> 3) * 1600 + (g & 7) * 40;  // ic*1600 + ky*40
      short8_t bf = ldg8(wrow + ks * 32);
      short8_t a0 = ldsh8(&s_in[aoff + ab0]);
      short8_t a1 = ldsh8(&s_in[aoff + ab1]);
      short8_t a2 = ldsh8(&s_in[aoff + ab2]);
      acc0 = __builtin_amdgcn_mfma_f32_16x16x32_bf16(a0, bf, acc0, 0, 0, 0);
      acc1 = __builtin_amdgcn_mfma_f32_16x16x32_bf16(a1, bf, acc1, 0, 0, 0);
      acc2 = __builtin_amdgcn_mfma_f32_16x16x32_bf16(a2, bf, acc2, 0, 0, 0);
    }
    const int oc = nt * 16 + lrow;
    const float bias = ld1(b1, oc, fw);
#pragma unroll
    for (int r = 0; r < 4; ++r) {
      int p0 = mt0 * 16 + lk8 * 4 + r;    // D row = (lane>>4)*4 + r
      float v0 = fmaxf(acc0[r] + bias, 0.f);
      float v1 = fmaxf(acc1[r] + bias, 0.f);
      float v2 = fmaxf(acc2[r] + bias, 0.f);
      if (p0 < 81)      s_f1[p0 * 40 + oc]        = f2bf(v0);
      if (p0 + 16 < 81) s_f1[(p0 + 16) * 40 + oc] = f2bf(v1);
      if (p0 + 32 < 81) s_f1[(p0 + 32) * 40 + oc] = f2bf(v2);
    }
  }
  __syncthreads();

  // ---- conv2: implicit GEMM  M=9(pad 16) x N=64 x K=512, k=(ky*4+kx)*32+ic ----
  // A 8-group = f1[(oy*2+ky)*9 + (ox*2+kx)][ic8*8..+8]  (16B contig, 16B aligned)
  {
    int p = lrow > 8 ? 8 : lrow;
    const int oy = p / 3, ox = p - (p / 3) * 3;
    const int pbase = (oy * 2) * 9 + (ox * 2);
    const int oc = wave * 16 + lrow;
    const ushort_t* w2row = w2pack + oc * 512 + lk8 * 8;
    f32x4_t acc = {0.f, 0.f, 0.f, 0.f};
#pragma unroll
    for (int s = 0; s < 16; ++s) {                      // s = ky*4+kx
      short8_t bf = ldg8(w2row + s * 32);
      const int pix = pbase + (s >> 2) * 9 + (s & 3);
      short8_t a = *(const short8_t*)&s_f1[pix * 40 + lk8 * 8];
      acc = __builtin_amdgcn_mfma_f32_16x16x32_bf16(a, bf, acc, 0, 0, 0);
    }
    const float bias = ld1(b2, oc, fw);
#pragma unroll
    for (int r = 0; r < 4; ++r) {
      const int pp = lk8 * 4 + r;
      if (pp < 9) s_f2[pp][oc] = fmaxf(acc[r] + bias, 0.f);
    }
  }
  __syncthreads();

  // ---- conv3 (VALU, bf16 weights): out[oc] = relu(b3 + sum_{ic,j} f2[j][ic]*w3[oc][ic*9+j]) ----
  {
    const int oc = tid & 63, q = tid >> 6;
    float a3 = 0.f;
    for (int i = 0; i < 16; ++i) {
      const int ic = q * 16 + i;
      const ushort_t* wp = w3pb + (ic * 9) * 64 + oc;
#pragma unroll
      for (int j = 0; j < 9; ++j) a3 += s_f2[j][ic] * bf2f(wp[j * 64]);
    }
    s_red[tid] = a3;
  }
  __syncthreads();
  if (tid < 64) {
    float v = ld1(b3, tid, fw) + s_red[tid] + s_red[64 + tid] + s_red[128 + tid] + s_red[192 + tid];
    s_f3[tid] = fmaxf(v, 0.f);
  }
  __syncthreads();

  // ---- gi = feats @ w_ih^T ----
  if (tid < 192) {
    float v = 0.f;
    for (int k = 0; k < 64; ++k) v += s_f3[k] * wihp[k * 192 + tid];
    gi[(size_t)img * G3 + tid] = v;
  }
}

// ---------------- GRU: one block (1 wave) per (b,n) sequence (verified R4) ----------------
__global__ __launch_bounds__(64) void gru_kernel(
    const float* __restrict__ gi, const void* __restrict__ h0,
    const void* __restrict__ whh, const void* __restrict__ bih,
    const void* __restrict__ bhh, const int* __restrict__ flags,
    float* __restrict__ rnn, float* __restrict__ hout) {
  __shared__ float s_w[G3 * 68];
  __shared__ float s_h[HID];
  const int j = threadIdx.x;
  const int s = blockIdx.x;
  const int fw = flags[1];

  if (fw) {
    const uint4* wsrc = reinterpret_cast<const uint4*>(whh);
    for (int v = j; v < (G3 * HID) / 8; v += 64) {
      uint4 w = wsrc[v];
      int i8 = v * 8;
      float* d = &s_w[(i8 >> 6) * 68 + (i8 & 63)];
      unpack2(w.x, d[0], d[1]);
      unpack2(w.y, d[2], d[3]);
      unpack2(w.z, d[4], d[5]);
      unpack2(w.w, d[6], d[7]);
    }
  } else {
    const float4* wsrc = reinterpret_cast<const float4*>(whh);
    for (int v = j; v < (G3 * HID) / 4; v += 64) {
      float4 w = wsrc[v];
      int i4 = v * 4;
      float* d = &s_w[(i4 >> 6) * 68 + (i4 & 63)];
      d[0] = w.x; d[1] = w.y; d[2] = w.z; d[3] = w.w;
    }
  }
  float h = ld1(h0, s * HID + j, fw);
  s_h[j] = h;
  const float bir = ld1(bih, j, fw), biz = ld1(bih, 64 + j, fw), bin_ = ld1(bih, 128 + j, fw);
  const float bhr = ld1(bhh, j, fw), bhz = ld1(bhh, 64 + j, fw), bhn = ld1(bhh, 128 + j, fw);
  const int b = s >> 3, n = s & 7;
  const float* gbase = gi + ((size_t)b * Ll * Nn + n) * G3;
  float* rbase = rnn + ((size_t)b * Ll * Nn + n) * HID;
  __syncthreads();

  const float* wr = &s_w[j * 68];
  const float* wz = &s_w[(64 + j) * 68];
  const float* wn = &s_w[(128 + j) * 68];

  for (int l = 0; l < Ll; ++l) {
    const float* g = gbase + (size_t)l * Nn * G3;
    float hr = bhr, hz = bhz, hn = bhn;
#pragma unroll 4
    for (int k = 0; k < 64; k += 4) {
      float4 hv = *reinterpret_cast<const float4*>(&s_h[k]);
      float4 w0 = *reinterpret_cast<const float4*>(wr + k);
      float4 w1v = *reinterpret_cast<const float4*>(wz + k);
      float4 w2v = *reinterpret_cast<const float4*>(wn + k);
      hr += w0.x * hv.x + w0.y * hv.y + w0.z * hv.z + w0.w * hv.w;
      hz += w1v.x * hv.x + w1v.y * hv.y + w1v.z * hv.z + w1v.w * hv.w;
      hn += w2v.x * hv.x + w2v.y * hv.y + w2v.z * hv.z + w2v.w * hv.w;
    }
    const float gr = g[j] + bir + hr;
    const float gz = g[64 + j] + biz + hz;
    const float gn = g[128 + j] + bin_;
    const float r = 1.f / (1.f + __expf(-gr));
    const float z = 1.f / (1.f + __expf(-gz));
    const float nn_ = tanhf(gn + r * hn);
    h = (1.f - z) * nn_ + z * h;
    __syncthreads();
    s_h[j] = h;
    rbase[(size_t)l * Nn * HID + j] = h;
    __syncthreads();
  }
  hout[(size_t)s * HID + j] = h;
}

// ---------------- FC: q = rnn @ fc_w^T + fc_b (verified R4) ----------------
__global__ __launch_bounds__(256) void fc_kernel(
    const float* __restrict__ rnn, const void* __restrict__ fcw,
    const void* __restrict__ fcb, const int* __restrict__ flags,
    float* __restrict__ q) {
  __shared__ float s_w[NACT * HID];
  __shared__ float s_b[NACT];
  const int tid = threadIdx.x;
  const int fw = flags[1];
  for (int i = tid; i < NACT * HID; i += 256) s_w[i] = ld1(fcw, i, fw);
  if (tid < NACT) s_b[tid] = ld1(fcb, tid, fw);
  __syncthreads();
  const int row = blockIdx.x * 256 + tid;
  float x[64];
  const float4* xp = reinterpret_cast<const float4*>(rnn + (size_t)row * HID);
#pragma unroll
  for (int i = 0; i < 16; ++i) {
    float4 v = xp[i];
    x[4 * i] = v.x; x[4 * i + 1] = v.y; x[4 * i + 2] = v.z; x[4 * i + 3] = v.w;
  }
#pragma unroll
  for (int a = 0; a < NACT; ++a) {
    float v = s_b[a];
#pragma unroll
    for (int k = 0; k < 64; ++k) v += x[k] * s_w[a * 64 + k];
    q[(size_t)row * NACT + a] = v;
  }
}

extern "C" void kernel_launch(void* const* d_in, const int* in_sizes, int n_in,
                              void* d_out, int out_size, void* d_ws, size_t ws_size,
                              hipStream_t stream) {
  const void* obs = d_in[0];
  const void* h0  = d_in[1];
  const void* w1  = d_in[2];
  const void* b1  = d_in[3];
  const void* w2  = d_in[4];
  const void* b2  = d_in[5];
  const void* w3  = d_in[6];
  const void* b3  = d_in[7];
  const void* wih = d_in[8];
  const void* whh = d_in[9];
  const void* bih = d_in[10];
  const void* bhh = d_in[11];
  const void* fcw = d_in[12];
  const void* fcb = d_in[13];

  float* qout = (float*)d_out;                        // (B,L,N,8) f32
  float* hout = qout + (size_t)IMGS * NACT;           // (B,N,64)  f32

  // workspace (~17.0 MB); every section offset is 16B-aligned
  char* wsb = (char*)d_ws;
  int*      flags  = (int*)wsb;                               // 16 B
  float*    wihp   = (float*)(wsb + 16);                      // 12288 f32
  float*    gi     = wihp + 12288;                            // IMGS*192 f32
  float*    rnn    = gi + (size_t)IMGS * G3;                  // IMGS*64 f32
  ushort_t* w1pack = (ushort_t*)(rnn + (size_t)IMGS * HID);   // 6144 bf16
  ushort_t* w2pack = w1pack + 6144;                           // 32768 bf16
  ushort_t* w3pb   = w2pack + 32768;                          // 36864 bf16

  detect_kernel<<<1, 256, 0, stream>>>((const ushort_t*)obs, (const ushort_t*)whh, flags);
  repack_kernel<<<144, 256, 0, stream>>>(w1, w2, w3, wih, flags, w1pack, w2pack, w3pb, wihp);
  conv_mfma_kernel<<<IMGS, 256, 0, stream>>>(obs, w1pack, w2pack, w3pb, b1, b2, b3, wihp, flags, gi);
  gru_kernel<<<256, 64, 0, stream>>>(gi, h0, whh, bih, bhh, flags, rnn, hout);
  fc_kernel<<<IMGS / 256, 256, 0, stream>>>(rnn, fcw, fcb, flags, qout);
}